// Round 13
// baseline (233.050 us; speedup 1.0000x reference)
//
#include <hip/hip_runtime.h>

#define NPTS   2048
#define TPB    768     // 12 waves; 4 cells/lane; 256-cell window per wave
#define BCELLS 1536    // block window: own 1024 + 512 block-ghost wedge

typedef float v4f __attribute__((ext_vector_type(4)));
typedef float v2f __attribute__((ext_vector_type(2)));

__device__ __forceinline__ v2f s2(float x) { v2f v; v.x = x; v.y = x; return v; }

// packed fma: lowers to v_pk_fma_f32 (2 f32 FMA / lane / instr)
__device__ __forceinline__ v2f fma2(v2f a, v2f b, v2f c) {
#if __has_builtin(__builtin_elementwise_fma)
    return __builtin_elementwise_fma(a, b, c);
#else
    v2f r; r.x = fmaf(a.x, b.x, c.x); r.y = fmaf(a.y, b.y, c.y); return r;
#endif
}

// g = 0.5*f(u) = u*(0.75 + u*(9.375 + u*(-25.25 + u*(18.75 - 3.125 u^2))))
// p = f'(u)    = 1.5 + u*(37.5 + u*(-151.5 + u*(150 - 37.5 u^2)))
__device__ __forceinline__ void eval_gp2(v2f u, v2f& g, v2f& p) {
    const v2f uu = u * u;
    v2f gg = fma2(uu, s2(-3.125f), s2(18.75f));
    gg = fma2(u, gg, s2(-25.25f));
    gg = fma2(u, gg, s2(9.375f));
    gg = fma2(u, gg, s2(0.75f));
    g = u * gg;
    v2f pp = fma2(uu, s2(-37.5f), s2(150.0f));
    pp = fma2(u, pp, s2(-151.5f));
    pp = fma2(u, pp, s2(37.5f));
    p = fma2(u, pp, s2(1.5f));
}

#define FLUX(gl, gr, pl, pr, ul, ur) \
    fmaf(-0.5f * fmaxf(fabsf(pl), fabsf(pr)), (ur) - (ul), (gl) + (gr))

// Grid = 2 blocks/row. Block (r,h) evolves 1536 cells (own 1024 + 512
// block-ghost; junk moves 1 cell/step -> own exact through t=499).
// WAVE-AUTONOMOUS: each wave holds a 256-cell register window (own 128 +
// 64-wedge/side, 4 cells/lane); halos via intra-wave shuffles; NO per-step
// barrier. Every 64 steps: block exchange via LDS re-canonicalizes windows.
__global__ __launch_bounds__(TPB) void lxf_wave(
    const float* __restrict__ init, float* __restrict__ out,
    int nbatch, int nsteps)
{
    __shared__ float UALL[BCELLS];

    const int blk  = blockIdx.x;
    const int r    = blk >> 1;          // row
    const int h    = blk & 1;           // 0 -> global [0,1536), 1 -> [512,2048)
    const int tid  = threadIdx.x;
    const int w    = tid >> 6;          // wave 0..11
    const int lane = tid & 63;
    const int goff = h ? 512 : 0;
    const size_t rowoff = (size_t)r * NPTS;
    const float lam = 0.1024f;          // DT/DX (exact in f32)

    // wave window base (edge waves have one-sided wedges)
    const int base = (w == 0) ? 0 : ((w == 11) ? 1280 : 128 * w - 64);
    const int c0   = base + 4 * lane;   // local index of lane's first cell

    // own-cell lanes (lane-aligned by construction)
    const int  ol0      = (w == 0) ? 0 : ((w == 11) ? 32 : 16);
    const bool own_lane = (lane >= ol0) && (lane < ol0 + 32);
    const bool stmask   = own_lane && (h ? (w >= 4) : (w <= 7));

    const bool bcL = (h == 0) && (w == 0)  && (lane == 0);   // global cell 0
    const bool bcR = (h == 1) && (w == 11) && (lane == 63);  // global cell 2047

    // ---- load window, eval g/p, write t=0 ----
    v4f uv = *reinterpret_cast<const v4f*>(init + rowoff + goff + c0);
    float u0 = uv.x, u1 = uv.y, u2 = uv.z, u3 = uv.w;
    float g0, g1, g2, g3, p0, p1, p2, p3;
    {
        v2f a, ga, pa, b, gb2, pb2;
        a.x = u0; a.y = u1; eval_gp2(a, ga, pa);
        b.x = u2; b.y = u3; eval_gp2(b, gb2, pb2);
        g0 = ga.x; g1 = ga.y; g2 = gb2.x; g3 = gb2.y;
        p0 = pa.x; p1 = pa.y; p2 = pb2.x; p3 = pb2.y;
    }

    float* dst = out + rowoff + goff + c0;
    if (stmask) *reinterpret_cast<v4f*>(dst) = uv;

    const size_t stride = (size_t)nbatch * NPTS;
    const int S = nsteps - 1;           // 499 advance steps
    int done = 0;

    while (done < S) {
        int Kr = S - done;
        if (Kr > 64) Kr = 64;

        for (int k = 0; k < Kr; ++k) {
            dst += stride;
            // halos from neighbor lanes (lane 0/63 self-clamp = wedge junk,
            // or discarded by bc at true boundaries)
            const float uL = __shfl_up(u3, 1);
            const float gL = __shfl_up(g3, 1);
            const float pL = __shfl_up(p3, 1);
            const float uR = __shfl_down(u0, 1);
            const float gR = __shfl_down(g0, 1);
            const float pR = __shfl_down(p0, 1);

            const float F0 = FLUX(gL, g0, pL, p0, uL, u0);
            const float F1 = FLUX(g0, g1, p0, p1, u0, u1);
            const float F2 = FLUX(g1, g2, p1, p2, u1, u2);
            const float F3 = FLUX(g2, g3, p2, p3, u2, u3);
            const float F4 = FLUX(g3, gR, p3, pR, u3, uR);

            float n0 = fmaf(-lam, F1 - F0, u0);
            float n1 = fmaf(-lam, F2 - F1, u1);
            float n2 = fmaf(-lam, F3 - F2, u2);
            float n3 = fmaf(-lam, F4 - F3, u3);
            n0 = bcL ? n1 : n0;   // u[0]   = u[1]
            n3 = bcR ? n2 : n3;   // u[N-1] = u[N-2]
            u0 = n0; u1 = n1; u2 = n2; u3 = n3;

            v2f a, ga, pa, b, gb2, pb2;
            a.x = u0; a.y = u1; eval_gp2(a, ga, pa);
            b.x = u2; b.y = u3; eval_gp2(b, gb2, pb2);
            g0 = ga.x; g1 = ga.y; g2 = gb2.x; g3 = gb2.y;
            p0 = pa.x; p1 = pa.y; p2 = pb2.x; p3 = pb2.y;

            if (stmask) {
                v4f wv; wv.x = u0; wv.y = u1; wv.z = u2; wv.w = u3;
                *reinterpret_cast<v4f*>(dst) = wv;
            }
        }
        done += Kr;

        if (done < S) {
            // ---- exchange: re-canonicalize windows from owning waves ----
            __syncthreads();
            if (own_lane) {
                v4f wv; wv.x = u0; wv.y = u1; wv.z = u2; wv.w = u3;
                *reinterpret_cast<v4f*>(&UALL[c0]) = wv;
            }
            __syncthreads();
            v4f rv = *reinterpret_cast<const v4f*>(&UALL[c0]);
            u0 = rv.x; u1 = rv.y; u2 = rv.z; u3 = rv.w;
            v2f a, ga, pa, b, gb2, pb2;
            a.x = u0; a.y = u1; eval_gp2(a, ga, pa);
            b.x = u2; b.y = u3; eval_gp2(b, gb2, pb2);
            g0 = ga.x; g1 = ga.y; g2 = gb2.x; g3 = gb2.y;
            p0 = pa.x; p1 = pa.y; p2 = pb2.x; p3 = pb2.y;
        }
    }
}

extern "C" void kernel_launch(void* const* d_in, const int* in_sizes, int n_in,
                              void* d_out, int out_size, void* d_ws, size_t ws_size,
                              hipStream_t stream) {
    const float* init = (const float*)d_in[0];
    float* out = (float*)d_out;

    const int nbatch = in_sizes[0] / NPTS;       // 128
    const int nsteps = out_size / in_sizes[0];   // 500

    hipLaunchKernelGGL(lxf_wave, dim3(2 * nbatch), dim3(TPB), 0, stream,
                       init, out, nbatch, nsteps);
}

// Round 14
// 171.351 us; speedup vs baseline: 1.3601x; 1.3601x over previous
//
#include <hip/hip_runtime.h>

#define NPTS 2048
#define TPB  768    // 12 waves/block; 2 cells/thread; capacity 1536
#define CAP  1536   // own 1024 + 512 ghost wedge (>= 499 steps of cone)

typedef float v2f __attribute__((ext_vector_type(2)));

// Barrier WITHOUT the vmcnt(0) drain __syncthreads() would emit:
// LDS writes must be visible (lgkmcnt), global stores may stay in flight.
#define EDGE_BARRIER() do {                                   \
    asm volatile("s_waitcnt lgkmcnt(0)" ::: "memory");        \
    __builtin_amdgcn_s_barrier();                             \
    asm volatile("" ::: "memory");                            \
} while (0)

__device__ __forceinline__ v2f s2(float x) { v2f v; v.x = x; v.y = x; return v; }

// packed fma: lowers to v_pk_fma_f32 (2 f32 FMA / lane / instr)
__device__ __forceinline__ v2f fma2(v2f a, v2f b, v2f c) {
#if __has_builtin(__builtin_elementwise_fma)
    return __builtin_elementwise_fma(a, b, c);
#else
    v2f r; r.x = fmaf(a.x, b.x, c.x); r.y = fmaf(a.y, b.y, c.y); return r;
#endif
}

// g = 0.5*f(u) = u*(0.75 + u*(9.375 + u*(-25.25 + u*(18.75 - 3.125 u^2))))
// q = 0.5*|f'(u)|,  f' = 1.5 + u*(37.5 + u*(-151.5 + u*(150 - 37.5 u^2)))
// Publishing q instead of p is bit-exact for the flux:
// 0.5*max(|pl|,|pr|) == max(0.5|pl|, 0.5|pr|)  (exact pow2 scaling).
__device__ __forceinline__ void eval_gq2(v2f u, v2f& g, v2f& q) {
    const v2f uu = u * u;
    v2f gg = fma2(uu, s2(-3.125f), s2(18.75f));
    gg = fma2(u, gg, s2(-25.25f));
    gg = fma2(u, gg, s2(9.375f));
    gg = fma2(u, gg, s2(0.75f));
    g = u * gg;
    v2f pp = fma2(uu, s2(-37.5f), s2(150.0f));
    pp = fma2(u, pp, s2(-151.5f));
    pp = fma2(u, pp, s2(37.5f));
    v2f p = fma2(u, pp, s2(1.5f));
    v2f ap; ap.x = fabsf(p.x); ap.y = fabsf(p.y);
    q = ap * s2(0.5f);
}

// Grid = 2 blocks per row (256 blocks -> all 256 CUs). Block (r,h) evolves
// 1536 cells autonomously: own 1024 + 512-wide ghost wedge toward the
// partner; clamp/garbage at the far edge advances 1 cell/step so own cells
// are bit-exact through t=499. LDS publishes (u, g, q) per cell in plane
// layout; halo reads are base+[0]/[3] dword pairs (ds_read2_b32-fusable).
__global__ __launch_bounds__(TPB) void lxf_split(
    const float* __restrict__ init, float* __restrict__ out,
    int nbatch, int nsteps)
{
    __shared__ float Ub[2][CAP];   // u
    __shared__ float Gb[2][CAP];   // g = 0.5*f(u)
    __shared__ float Qb[2][CAP];   // q = 0.5*|f'(u)|

    const int blk = blockIdx.x;
    const int r   = blk >> 1;            // row
    const int h   = blk & 1;             // 0 -> global [0,1536), 1 -> [512,2048)
    const int tid = threadIdx.x;
    const int c0  = 2 * tid;             // local first cell
    const int gb  = h ? 512 : 0;
    const size_t rowoff = (size_t)r * NPTS;
    const float lam = 0.1024f;           // DT/DX (exact in f32)

    const bool st  = h ? (c0 >= 512) : (c0 < 1024);      // own-cell store mask
    const bool bcL = (h == 0) && (tid == 0);             // global cell 0
    const bool bcR = (h == 1) && (tid == TPB - 1);       // global cell 2047
    // cone distance into the wedge (margin 2); active while dist <= rem
    const int dist = h ? (509 - c0) : (c0 - 1025);

    // ---- load init cells, eval g/q, write t=0, publish buf 0 ----
    v2f uv = *reinterpret_cast<const v2f*>(init + rowoff + gb + c0);
    v2f gv, qv;
    eval_gq2(uv, gv, qv);

    if (st) *reinterpret_cast<v2f*>(out + rowoff + gb + c0) = uv;

    *reinterpret_cast<v2f*>(&Ub[0][c0]) = uv;
    *reinterpret_cast<v2f*>(&Gb[0][c0]) = gv;
    *reinterpret_cast<v2f*>(&Qb[0][c0]) = qv;
    EDGE_BARRIER();

    const size_t stride = (size_t)nbatch * NPTS;    // floats per step
    float* dstw = out + rowoff + gb + c0;

// Halo loads: base = &plane[c0-1]; [0] = left halo (cell c0-1), [3] = right
// halo (cell c0+2). Unclamped: tid 0's [0] and tid TPB-1's [3] read
// garbage that is either overridden (true boundary) or stays in the junk
// cone (wedge edge / deactivated-frontier region).
#define STEP(CUR, NXT) do {                                              \
    dstw += stride;                                                      \
    if (dist <= rem) {                                                   \
        const float* bu = &Ub[CUR][0] + (c0 - 1);                        \
        const float* bg = &Gb[CUR][0] + (c0 - 1);                        \
        const float* bq = &Qb[CUR][0] + (c0 - 1);                        \
        float uL = bu[0], uR = bu[3];                                    \
        float gL = bg[0], gR = bg[3];                                    \
        float qL = bq[0], qR = bq[3];                                    \
        if (tid == 0)       { uL = uv.x; gL = gv.x; qL = qv.x; }         \
        if (tid == TPB - 1) { uR = uv.y; gR = gv.y; qR = qv.y; }         \
        const float aL = fmaxf(qL, qv.x);                                \
        const float aM = fmaxf(qv.x, qv.y);                              \
        const float aR = fmaxf(qv.y, qR);                                \
        const float fhL = fmaf(-aL, uv.x - uL, gL + gv.x);               \
        const float fhM = fmaf(-aM, uv.y - uv.x, gv.x + gv.y);           \
        const float fhR = fmaf(-aR, uR - uv.y, gv.y + gR);               \
        float n0 = fmaf(-lam, fhM - fhL, uv.x);                          \
        float n1 = fmaf(-lam, fhR - fhM, uv.y);                          \
        if (bcL) n0 = n1;   /* u[0]   = u[1]   */                        \
        if (bcR) n1 = n0;   /* u[N-1] = u[N-2] */                        \
        uv.x = n0; uv.y = n1;                                            \
        eval_gq2(uv, gv, qv);                                            \
        *reinterpret_cast<v2f*>(&Ub[NXT][c0]) = uv;                      \
        *reinterpret_cast<v2f*>(&Gb[NXT][c0]) = gv;                      \
        *reinterpret_cast<v2f*>(&Qb[NXT][c0]) = qv;                      \
        if (st) *reinterpret_cast<v2f*>(dstw) = uv;                      \
    }                                                                    \
    --rem;                                                               \
    EDGE_BARRIER();                                                      \
} while (0)

    const int S  = nsteps - 1;   // 499 advance steps
    int rem = S - 1;             // steps remaining AFTER the current one
    const int P2 = S >> 1;       // 249
    for (int i = 0; i < P2; ++i) {
        STEP(0, 1);
        STEP(1, 0);
    }
    if (S & 1) STEP(0, 1);
#undef STEP
}

extern "C" void kernel_launch(void* const* d_in, const int* in_sizes, int n_in,
                              void* d_out, int out_size, void* d_ws, size_t ws_size,
                              hipStream_t stream) {
    const float* init = (const float*)d_in[0];
    float* out = (float*)d_out;

    const int nbatch = in_sizes[0] / NPTS;       // 128
    const int nsteps = out_size / in_sizes[0];   // 500

    hipLaunchKernelGGL(lxf_split, dim3(2 * nbatch), dim3(TPB), 0, stream,
                       init, out, nbatch, nsteps);
}

// Round 16
// 170.777 us; speedup vs baseline: 1.3646x; 1.0034x over previous
//
#include <hip/hip_runtime.h>

#define NPTS   2048
#define TPB    576     // 9 waves/block; 2 cells/thread; window 1152
#define WIN    1152    // own 1024 + 128 time-chunk wedge (one side)
#define TCHUNK 125     // steps per launch; wedge 128 > 125+2 -> own exact

typedef float v2f __attribute__((ext_vector_type(2)));

// Barrier WITHOUT the vmcnt(0) drain __syncthreads() would emit:
// LDS writes must be visible (lgkmcnt), global stores may stay in flight.
#define EDGE_BARRIER() do {                                   \
    asm volatile("s_waitcnt lgkmcnt(0)" ::: "memory");        \
    __builtin_amdgcn_s_barrier();                             \
    asm volatile("" ::: "memory");                            \
} while (0)

__device__ __forceinline__ v2f s2(float x) { v2f v; v.x = x; v.y = x; return v; }

// packed fma: lowers to v_pk_fma_f32 (2 f32 FMA / lane / instr)
__device__ __forceinline__ v2f fma2(v2f a, v2f b, v2f c) {
#if __has_builtin(__builtin_elementwise_fma)
    return __builtin_elementwise_fma(a, b, c);
#else
    v2f r; r.x = fmaf(a.x, b.x, c.x); r.y = fmaf(a.y, b.y, c.y); return r;
#endif
}

// g = 0.5*f(u) = u*(0.75 + u*(9.375 + u*(-25.25 + u*(18.75 - 3.125 u^2))))
// q = 0.5*|f'(u)|; flux uses max(q) -- bit-exact vs 0.5*max|p| (pow2 scale).
__device__ __forceinline__ void eval_gq2(v2f u, v2f& g, v2f& q) {
    const v2f uu = u * u;
    v2f gg = fma2(uu, s2(-3.125f), s2(18.75f));
    gg = fma2(u, gg, s2(-25.25f));
    gg = fma2(u, gg, s2(9.375f));
    gg = fma2(u, gg, s2(0.75f));
    g = u * gg;
    v2f pp = fma2(uu, s2(-37.5f), s2(150.0f));
    pp = fma2(u, pp, s2(-151.5f));
    pp = fma2(u, pp, s2(37.5f));
    v2f p = fma2(u, pp, s2(1.5f));
    v2f ap; ap.x = fabsf(p.x); ap.y = fabsf(p.y);
    q = ap * s2(0.5f);
}

// Time-chunked: each launch advances nsub (<=125) steps. Block (r,h) holds
// own 1024 cells + a 128-cell wedge toward the partner; junk moves 1
// cell/step so own cells are bit-exact within the launch. Launch k reads
// row t0 from `srcrow` (init or out's row t0, written by launch k-1; same
// stream => ordered). STEP body identical to the R8-proven kernel.
__global__ __launch_bounds__(TPB) void lxf_tc(
    const float* __restrict__ srcrow, float* __restrict__ out,
    int nbatch, int t0, int nsub, int copy0)
{
    __shared__ float Ub[2][WIN];   // u
    __shared__ float Gb[2][WIN];   // g = 0.5*f(u)
    __shared__ float Qb[2][WIN];   // q = 0.5*|f'(u)|

    const int blk = blockIdx.x;
    const int r   = blk >> 1;            // row
    const int h   = blk & 1;             // 0 -> global [0,1152), 1 -> [896,2048)
    const int tid = threadIdx.x;
    const int c0  = 2 * tid;             // local first cell
    const int wb  = h ? (NPTS - WIN) : 0;   // window base (896 or 0)
    const float lam = 0.1024f;           // DT/DX (exact in f32)

    const bool st  = h ? (c0 >= 128) : (c0 < 1024);      // own-cell store mask
    const bool bcL = (h == 0) && (tid == 0);             // global cell 0
    const bool bcR = (h == 1) && (tid == TPB - 1);       // global cell 2047
    const int  hl  = (tid == 0)       ? 0       : c0 - 1;
    const int  hr  = (tid == TPB - 1) ? WIN - 1 : c0 + 2;
    // cone distance from pair to own region (margin 2); active while <= rem
    const int dist = h ? (125 - c0) : (c0 - 1025);

    // ---- load state at t0 (window always within the row), eval, publish ----
    v2f uv = *reinterpret_cast<const v2f*>(srcrow + (size_t)r * NPTS + wb + c0);
    v2f gv, qv;
    eval_gq2(uv, gv, qv);

    const size_t stride = (size_t)nbatch * NPTS;    // floats per step
    float* sp = out + (size_t)t0 * stride + (size_t)r * NPTS + (wb + c0);
    if (copy0 && st) *reinterpret_cast<v2f*>(sp) = uv;   // t=0 copy

    *reinterpret_cast<v2f*>(&Ub[0][c0]) = uv;
    *reinterpret_cast<v2f*>(&Gb[0][c0]) = gv;
    *reinterpret_cast<v2f*>(&Qb[0][c0]) = qv;
    EDGE_BARRIER();

    float* dstw = sp;
    int rem = nsub - 1;   // steps remaining AFTER the current one

#define STEP(CUR, NXT) do {                                              \
    dstw += stride;                                                      \
    if (dist <= rem) {                                                   \
        const float uL = Ub[CUR][hl], gL = Gb[CUR][hl], qL = Qb[CUR][hl];\
        const float uR = Ub[CUR][hr], gR = Gb[CUR][hr], qR = Qb[CUR][hr];\
        const float aL = fmaxf(qL, qv.x);                                \
        const float aM = fmaxf(qv.x, qv.y);                              \
        const float aR = fmaxf(qv.y, qR);                                \
        const float fhL = fmaf(-aL, uv.x - uL, gL + gv.x);               \
        const float fhM = fmaf(-aM, uv.y - uv.x, gv.x + gv.y);           \
        const float fhR = fmaf(-aR, uR - uv.y, gv.y + gR);               \
        float n0 = fmaf(-lam, fhM - fhL, uv.x);                          \
        float n1 = fmaf(-lam, fhR - fhM, uv.y);                          \
        if (bcL) n0 = n1;   /* u[0]   = u[1]   */                        \
        if (bcR) n1 = n0;   /* u[N-1] = u[N-2] */                        \
        uv.x = n0; uv.y = n1;                                            \
        eval_gq2(uv, gv, qv);                                            \
        *reinterpret_cast<v2f*>(&Ub[NXT][c0]) = uv;                      \
        *reinterpret_cast<v2f*>(&Gb[NXT][c0]) = gv;                      \
        *reinterpret_cast<v2f*>(&Qb[NXT][c0]) = qv;                      \
        if (st) *reinterpret_cast<v2f*>(dstw) = uv;                      \
    }                                                                    \
    --rem;                                                               \
    EDGE_BARRIER();                                                      \
} while (0)

    const int P2 = nsub >> 1;
    for (int i = 0; i < P2; ++i) {
        STEP(0, 1);
        STEP(1, 0);
    }
    if (nsub & 1) STEP(0, 1);
#undef STEP
}

extern "C" void kernel_launch(void* const* d_in, const int* in_sizes, int n_in,
                              void* d_out, int out_size, void* d_ws, size_t ws_size,
                              hipStream_t stream) {
    const float* init = (const float*)d_in[0];
    float* out = (float*)d_out;

    const int nbatch = in_sizes[0] / NPTS;       // 128
    const int nsteps = out_size / in_sizes[0];   // 500
    const int S = nsteps - 1;                    // 499 advance steps
    const size_t stride = (size_t)nbatch * NPTS;

    int t0 = 0;
    int first = 1;
    while (t0 < S) {
        int nsub = S - t0;
        if (nsub > TCHUNK) nsub = TCHUNK;
        const float* srcrow = first ? init : (out + (size_t)t0 * stride);
        hipLaunchKernelGGL(lxf_tc, dim3(2 * nbatch), dim3(TPB), 0, stream,
                           srcrow, out, nbatch, t0, nsub, first);
        t0 += nsub;
        first = 0;
    }
}

// Round 17
// 155.585 us; speedup vs baseline: 1.4979x; 1.0976x over previous
//
#include <hip/hip_runtime.h>

#define NPTS 2048
#define TPB  768    // 12 waves/block; 2 cells/thread; capacity 1536
#define CAP  1536   // own 1024 + 512 ghost wedge (>= 499 steps of cone)

typedef float v2f __attribute__((ext_vector_type(2)));

// Barrier WITHOUT the vmcnt(0) drain __syncthreads() would emit:
// LDS writes must be visible (lgkmcnt), global stores may stay in flight.
#define EDGE_BARRIER() do {                                   \
    asm volatile("s_waitcnt lgkmcnt(0)" ::: "memory");        \
    __builtin_amdgcn_s_barrier();                             \
    asm volatile("" ::: "memory");                            \
} while (0)

__device__ __forceinline__ v2f s2(float x) { v2f v; v.x = x; v.y = x; return v; }

// packed fma: lowers to v_pk_fma_f32 (2 f32 FMA / lane / instr)
__device__ __forceinline__ v2f fma2(v2f a, v2f b, v2f c) {
#if __has_builtin(__builtin_elementwise_fma)
    return __builtin_elementwise_fma(a, b, c);
#else
    v2f r; r.x = fmaf(a.x, b.x, c.x); r.y = fmaf(a.y, b.y, c.y); return r;
#endif
}

// g = 0.5*f(u) = u*(0.75 + u*(9.375 + u*(-25.25 + u*(18.75 - 3.125 u^2))))
// p = f'(u)    = 1.5 + u*(37.5 + u*(-151.5 + u*(150 - 37.5 u^2)))
__device__ __forceinline__ void eval_gp2(v2f u, v2f& g, v2f& p) {
    const v2f uu = u * u;
    v2f gg = fma2(uu, s2(-3.125f), s2(18.75f));
    gg = fma2(u, gg, s2(-25.25f));
    gg = fma2(u, gg, s2(9.375f));
    gg = fma2(u, gg, s2(0.75f));
    g = u * gg;
    v2f pp = fma2(uu, s2(-37.5f), s2(150.0f));
    pp = fma2(u, pp, s2(-151.5f));
    pp = fma2(u, pp, s2(37.5f));
    p = fma2(u, pp, s2(1.5f));
}

// Grid = 2 blocks per row (256 blocks -> all 256 CUs). Block (r,h) evolves
// 1536 cells autonomously: own 1024 + 512-wide ghost wedge toward the
// partner; clamp junk advances 1 cell/step so own cells are bit-exact
// through t=499. R8-proven body; ONLY change: halo reads are aligned
// ds_read_b64 pairs (3 reads/step instead of 6 scalar reads).
__global__ __launch_bounds__(TPB) void lxf_split(
    const float* __restrict__ init, float* __restrict__ out,
    int nbatch, int nsteps)
{
    __shared__ float Ub[2][CAP];   // u
    __shared__ float Gb[2][CAP];   // g = 0.5*f(u)
    __shared__ float Pb[2][CAP];   // p = f'(u)

    const int blk = blockIdx.x;
    const int r   = blk >> 1;            // row
    const int h   = blk & 1;             // 0 -> global [0,1536), 1 -> [512,2048)
    const int tid = threadIdx.x;
    const int c0  = 2 * tid;             // local first cell
    const int gb  = h ? 512 : 0;         // local -> global offset
    const size_t rowoff = (size_t)r * NPTS;
    const float lam = 0.1024f;           // DT/DX (exact in f32)

    const bool st  = h ? (c0 >= 512) : (c0 < 1024);      // own-cell store mask
    const bool bcL = (h == 0) && (tid == 0);             // global cell 0
    const bool bcR = (h == 1) && (tid == TPB - 1);       // global cell 2047
    // aligned pair bases: left pair {u[c0-2], u[c0-1]}, right {u[c0+2], u[c0+3]}
    // tid 0 / TPB-1 clamps read garbage halos that are either overridden by
    // the bc or confined to the junk cone (own cells unaffected).
    const int  il  = (tid == 0)       ? 0       : c0 - 2;
    const int  ir  = (tid == TPB - 1) ? CAP - 2 : c0 + 2;
    // cone distance into the wedge (margin 2); active while dist <= rem
    const int dist = h ? (509 - c0) : (c0 - 1025);

    // ---- load init cells, eval g/p, write t=0, publish buf 0 ----
    v2f uv = *reinterpret_cast<const v2f*>(init + rowoff + gb + c0);
    v2f gv, pv;
    eval_gp2(uv, gv, pv);

    if (st) *reinterpret_cast<v2f*>(out + rowoff + gb + c0) = uv;

    *reinterpret_cast<v2f*>(&Ub[0][c0]) = uv;
    *reinterpret_cast<v2f*>(&Gb[0][c0]) = gv;
    *reinterpret_cast<v2f*>(&Pb[0][c0]) = pv;
    EDGE_BARRIER();

    const size_t stride = (size_t)nbatch * NPTS;    // floats per step
    float* dstw = out + rowoff + gb + c0;

#define STEP(CUR, NXT) do {                                              \
    dstw += stride;                                                      \
    if (dist <= rem) {                                                   \
        const v2f uLp = *reinterpret_cast<const v2f*>(&Ub[CUR][il]);     \
        const v2f uRp = *reinterpret_cast<const v2f*>(&Ub[CUR][ir]);     \
        const v2f gLp = *reinterpret_cast<const v2f*>(&Gb[CUR][il]);     \
        const v2f gRp = *reinterpret_cast<const v2f*>(&Gb[CUR][ir]);     \
        const v2f pLp = *reinterpret_cast<const v2f*>(&Pb[CUR][il]);     \
        const v2f pRp = *reinterpret_cast<const v2f*>(&Pb[CUR][ir]);     \
        const float uL = uLp.y, gL = gLp.y, pL = pLp.y;                  \
        const float uR = uRp.x, gR = gRp.x, pR = pRp.x;                  \
        const float aL = fmaxf(fabsf(pL), fabsf(pv.x));                  \
        const float aM = fmaxf(fabsf(pv.x), fabsf(pv.y));                \
        const float aR = fmaxf(fabsf(pv.y), fabsf(pR));                  \
        const float fhL = fmaf(-0.5f * aL, uv.x - uL, gL + gv.x);        \
        const float fhM = fmaf(-0.5f * aM, uv.y - uv.x, gv.x + gv.y);    \
        const float fhR = fmaf(-0.5f * aR, uR - uv.y, gv.y + gR);        \
        float n0 = fmaf(-lam, fhM - fhL, uv.x);                          \
        float n1 = fmaf(-lam, fhR - fhM, uv.y);                          \
        if (bcL) n0 = n1;   /* u[0]   = u[1]   */                        \
        if (bcR) n1 = n0;   /* u[N-1] = u[N-2] */                        \
        uv.x = n0; uv.y = n1;                                            \
        eval_gp2(uv, gv, pv);                                            \
        *reinterpret_cast<v2f*>(&Ub[NXT][c0]) = uv;                      \
        *reinterpret_cast<v2f*>(&Gb[NXT][c0]) = gv;                      \
        *reinterpret_cast<v2f*>(&Pb[NXT][c0]) = pv;                      \
        if (st) *reinterpret_cast<v2f*>(dstw) = uv;                      \
    }                                                                    \
    --rem;                                                               \
    EDGE_BARRIER();                                                      \
} while (0)

    const int S  = nsteps - 1;   // 499 advance steps
    int rem = S - 1;             // steps remaining AFTER the current one
    const int P2 = S >> 1;       // 249
    for (int i = 0; i < P2; ++i) {
        STEP(0, 1);
        STEP(1, 0);
    }
    if (S & 1) STEP(0, 1);
#undef STEP
}

extern "C" void kernel_launch(void* const* d_in, const int* in_sizes, int n_in,
                              void* d_out, int out_size, void* d_ws, size_t ws_size,
                              hipStream_t stream) {
    const float* init = (const float*)d_in[0];
    float* out = (float*)d_out;

    const int nbatch = in_sizes[0] / NPTS;       // 128
    const int nsteps = out_size / in_sizes[0];   // 500

    hipLaunchKernelGGL(lxf_split, dim3(2 * nbatch), dim3(TPB), 0, stream,
                       init, out, nbatch, nsteps);
}